// Round 10
// baseline (997.955 us; speedup 1.0000x reference)
//
#include <hip/hip_runtime.h>

// SimpleRNN fused kernel for MI355X (gfx950).
// B=256, T=512, I=64, H=256, O=1, fp32.
//
// History:
// R1: padded LDS half-split (conflicts 1.34e8 -> 0, 608 -> 461 us).
// R2-R6: knobs/GEMM failed; R7: LDS-issue fix (J=4/S=8 multi-j):
//     455 -> 319 us, VALUBusy 96% => VALU-ISSUE-bound at ~405
//     instr/thread/step (160 FMA + ~160 AGPR-spill-read tax + misc).
// R8: 1024thr variant: budget 128/wave -> remat regime, regressed.
// R9: pk_fma: issue halved but VALUBusy 51%, stalls (AGPR pair copies);
//     regressed 319->349. Reverted.
// R10: attack the tax via the BUDGET, not the allocator: register file is
//     512 regs/SIMD (m69). 256-thread block => 1 wave/SIMD => 512-reg
//     budget/wave (arch cap 256). J=8/S=8: lane (r=tid>>3,s=tid&7) owns
//     j-octet 8r..8r+7 x k-seg 32s..31 = 320 weight floats, 320 FMA.
//     Per-SIMD issue = 1 wave x (320+tax+misc) x 2cyc ~ 950-1000 vs R7's
//     1620, even if ~115 floats spill to AGPR. LDS: 10 reads/lane
//     (8 h-b128 shared by 8 j's + 2 x-b128) ~ 44 instr/CU/step.
//     Reduce-scatter over 8 s-lanes (xor 1,2,4): lane finalizes j=8r+s.
//     h layout = R7's padded slot(k)=k+4*(k>>5): reads at float4 idx
//     9s+c -> banks 4(s+c) mod 32, 8 disjoint groups, conflict-free.

#define RNN_B 256
#define RNN_T 512
#define RNN_I 64
#define RNN_H 256
#define TILE_T 16
#define N_TILES (RNN_T / TILE_T)

__global__
__attribute__((amdgpu_flat_work_group_size(256, 256), amdgpu_waves_per_eu(1, 1)))
void rnn_fused_kernel(const float* __restrict__ x,     // [B,T,I]
                      const float* __restrict__ W_ih,  // [H,I]
                      const float* __restrict__ W_hh,  // [H,H]
                      const float* __restrict__ b_ih,  // [H]
                      const float* __restrict__ b_hh,  // [H]
                      const float* __restrict__ fc_W,  // [O,H], O=1
                      const float* __restrict__ fc_b,  // [O]
                      float* __restrict__ out)         // [B,O]
{
    const int b   = blockIdx.x;
    const int tid = threadIdx.x;    // 0..255
    const int w   = tid >> 6;       // wave 0..3
    const int l   = tid & 63;       // lane
    const int r   = tid >> 3;       // j-octet index 0..31
    const int s   = tid & 7;        // k-segment 0..7
    const int j0  = r * 8;          // first j of this lane's octet

    __shared__ float hbuf[2][288];        // padded h: slot(k) = k + 4*(k>>5)
    __shared__ float xt[TILE_T][RNN_I];   // x tile: 16 timesteps, 4 KB
    __shared__ float red[4];

    // ---- persistent weights: 8 j-rows x 32-k segment (320 floats) ----
    float4 wh[8][8];   // wh[jj][c] = W_hh[j0+jj][32s + 4c .. +3]
    float4 wi[8][2];   // wi[jj][c] = W_ih[j0+jj][8s + 4c .. +3]
    #pragma unroll
    for (int jj = 0; jj < 8; ++jj) {
        const float4* src = reinterpret_cast<const float4*>(W_hh + (j0 + jj) * RNN_H + 32 * s);
        #pragma unroll
        for (int c = 0; c < 8; ++c) wh[jj][c] = src[c];
        const float4* s2 = reinterpret_cast<const float4*>(W_ih + (j0 + jj) * RNN_I + 8 * s);
        wi[jj][0] = s2[0];
        wi[jj][1] = s2[1];
    }

    // lane finalizes j_fin = j0 + s after the 3-round reduce-scatter
    const int   j_fin = j0 + s;
    const int   jslot = j_fin + 4 * (j_fin >> 5);
    const float bias2 = b_ih[j_fin] + b_hh[j_fin];
    const float fcw   = fc_W[j_fin];

    // ---- prologue: h0 = 0; prefetch x tile 0 into registers ----
    hbuf[0][tid] = 0.0f;
    if (tid < 32) hbuf[0][256 + tid] = 0.0f;
    const float4* xs = reinterpret_cast<const float4*>(x + (size_t)b * RNN_T * RNN_I);
    float4 xreg = xs[tid];   // tile 0: 256 float4 = 16 steps x 64 floats

    float hj = 0.0f;  // this lane's h_new[j_fin]

#define RNN_STEP(CUR, NXT, TT)                                                  \
    {                                                                           \
        const float4* hs = reinterpret_cast<const float4*>(hbuf[CUR]) + 9 * s;  \
        const float4* xp = reinterpret_cast<const float4*>(&xt[TT][0]) + 2 * s; \
        float a0=0.f,a1=0.f,a2=0.f,a3=0.f,a4=0.f,a5=0.f,a6=0.f,a7=0.f;          \
        _Pragma("unroll")                                                       \
        for (int c = 0; c < 8; ++c) {                                           \
            const float4 h4 = hs[c];  /* 8 addrs, 8 disjoint bank groups */     \
            a0 = fmaf(h4.x, wh[0][c].x, a0); a1 = fmaf(h4.x, wh[1][c].x, a1);   \
            a2 = fmaf(h4.x, wh[2][c].x, a2); a3 = fmaf(h4.x, wh[3][c].x, a3);   \
            a4 = fmaf(h4.x, wh[4][c].x, a4); a5 = fmaf(h4.x, wh[5][c].x, a5);   \
            a6 = fmaf(h4.x, wh[6][c].x, a6); a7 = fmaf(h4.x, wh[7][c].x, a7);   \
            a0 = fmaf(h4.y, wh[0][c].y, a0); a1 = fmaf(h4.y, wh[1][c].y, a1);   \
            a2 = fmaf(h4.y, wh[2][c].y, a2); a3 = fmaf(h4.y, wh[3][c].y, a3);   \
            a4 = fmaf(h4.y, wh[4][c].y, a4); a5 = fmaf(h4.y, wh[5][c].y, a5);   \
            a6 = fmaf(h4.y, wh[6][c].y, a6); a7 = fmaf(h4.y, wh[7][c].y, a7);   \
            a0 = fmaf(h4.z, wh[0][c].z, a0); a1 = fmaf(h4.z, wh[1][c].z, a1);   \
            a2 = fmaf(h4.z, wh[2][c].z, a2); a3 = fmaf(h4.z, wh[3][c].z, a3);   \
            a4 = fmaf(h4.z, wh[4][c].z, a4); a5 = fmaf(h4.z, wh[5][c].z, a5);   \
            a6 = fmaf(h4.z, wh[6][c].z, a6); a7 = fmaf(h4.z, wh[7][c].z, a7);   \
            a0 = fmaf(h4.w, wh[0][c].w, a0); a1 = fmaf(h4.w, wh[1][c].w, a1);   \
            a2 = fmaf(h4.w, wh[2][c].w, a2); a3 = fmaf(h4.w, wh[3][c].w, a3);   \
            a4 = fmaf(h4.w, wh[4][c].w, a4); a5 = fmaf(h4.w, wh[5][c].w, a5);   \
            a6 = fmaf(h4.w, wh[6][c].w, a6); a7 = fmaf(h4.w, wh[7][c].w, a7);   \
        }                                                                       \
        _Pragma("unroll")                                                       \
        for (int c = 0; c < 2; ++c) {                                           \
            const float4 x4 = xp[c];                                            \
            a0 = fmaf(x4.x, wi[0][c].x, a0); a1 = fmaf(x4.x, wi[1][c].x, a1);   \
            a2 = fmaf(x4.x, wi[2][c].x, a2); a3 = fmaf(x4.x, wi[3][c].x, a3);   \
            a4 = fmaf(x4.x, wi[4][c].x, a4); a5 = fmaf(x4.x, wi[5][c].x, a5);   \
            a6 = fmaf(x4.x, wi[6][c].x, a6); a7 = fmaf(x4.x, wi[7][c].x, a7);   \
            a0 = fmaf(x4.y, wi[0][c].y, a0); a1 = fmaf(x4.y, wi[1][c].y, a1);   \
            a2 = fmaf(x4.y, wi[2][c].y, a2); a3 = fmaf(x4.y, wi[3][c].y, a3);   \
            a4 = fmaf(x4.y, wi[4][c].y, a4); a5 = fmaf(x4.y, wi[5][c].y, a5);   \
            a6 = fmaf(x4.y, wi[6][c].y, a6); a7 = fmaf(x4.y, wi[7][c].y, a7);   \
            a0 = fmaf(x4.z, wi[0][c].z, a0); a1 = fmaf(x4.z, wi[1][c].z, a1);   \
            a2 = fmaf(x4.z, wi[2][c].z, a2); a3 = fmaf(x4.z, wi[3][c].z, a3);   \
            a4 = fmaf(x4.z, wi[4][c].z, a4); a5 = fmaf(x4.z, wi[5][c].z, a5);   \
            a6 = fmaf(x4.z, wi[6][c].z, a6); a7 = fmaf(x4.z, wi[7][c].z, a7);   \
            a0 = fmaf(x4.w, wi[0][c].w, a0); a1 = fmaf(x4.w, wi[1][c].w, a1);   \
            a2 = fmaf(x4.w, wi[2][c].w, a2); a3 = fmaf(x4.w, wi[3][c].w, a3);   \
            a4 = fmaf(x4.w, wi[4][c].w, a4); a5 = fmaf(x4.w, wi[5][c].w, a5);   \
            a6 = fmaf(x4.w, wi[6][c].w, a6); a7 = fmaf(x4.w, wi[7][c].w, a7);   \
        }                                                                       \
        /* reduce-scatter over the 8 k-seg lanes: keep jj-bit == s-bit */       \
        const bool b0 = (s & 1) != 0;                                           \
        const float k0 = b0 ? a1 : a0, g0 = b0 ? a0 : a1;                       \
        const float k1 = b0 ? a3 : a2, g1 = b0 ? a2 : a3;                       \
        const float k2 = b0 ? a5 : a4, g2 = b0 ? a4 : a5;                       \
        const float k3 = b0 ? a7 : a6, g3 = b0 ? a6 : a7;                       \
        const float q0 = k0 + __shfl_xor(g0, 1, 64);  /* jj = (s&1)     */      \
        const float q1 = k1 + __shfl_xor(g1, 1, 64);  /* jj = 2+(s&1)   */      \
        const float q2 = k2 + __shfl_xor(g2, 1, 64);  /* jj = 4+(s&1)   */      \
        const float q3 = k3 + __shfl_xor(g3, 1, 64);  /* jj = 6+(s&1)   */      \
        const bool b1 = (s & 2) != 0;                                           \
        const float m0 = b1 ? q1 : q0, n0 = b1 ? q0 : q1;                       \
        const float m1 = b1 ? q3 : q2, n1 = b1 ? q2 : q3;                       \
        const float u0 = m0 + __shfl_xor(n0, 2, 64);  /* jj = (s&3)     */      \
        const float u1 = m1 + __shfl_xor(n1, 2, 64);  /* jj = 4+(s&3)   */      \
        const bool b2 = (s & 4) != 0;                                           \
        const float mk = b2 ? u1 : u0, mg = b2 ? u0 : u1;                       \
        const float v  = mk + __shfl_xor(mg, 4, 64);  /* jj = s (full)  */      \
        const float z  = v + bias2;                                             \
        const float zc = fminf(fmaxf(z, -10.f), 10.f);                          \
        const float e  = exp2f(zc * 2.8853900817779268f);     /* e^(2z) */      \
        const float hn = (e - 1.f) * __builtin_amdgcn_rcpf(e + 1.f);            \
        hj = hn;                                                                \
        hbuf[NXT][jslot] = hn;   /* 64 lanes, 64 consec j -> 2-way, free */     \
        __syncthreads();                                                        \
    }

    for (int tile = 0; tile < N_TILES; ++tile) {
        // stage x tile (entering here, all waves are synced past old reads)
        {
            const int st = tid >> 4;            // step within tile
            const int of = (tid & 15) << 2;     // float offset in row
            *reinterpret_cast<float4*>(&xt[st][of]) = xreg;
        }
        if (tile + 1 < N_TILES) xreg = xs[(tile + 1) * 256 + tid];  // prefetch
        __syncthreads();   // xt (and h0/weights on tile 0) ready

        for (int tt = 0; tt < TILE_T; tt += 2) {
            RNN_STEP(0, 1, tt)
            RNN_STEP(1, 0, tt + 1)
        }
    }
#undef RNN_STEP

    // ---- epilogue: out[b] = sum_j h_T[j]*fc_W[j] + fc_b ----
    float term = hj * fcw;   // every thread holds exactly one j
    #pragma unroll
    for (int d = 1; d < 64; d <<= 1) term += __shfl_xor(term, d, 64);
    if (l == 0) red[w] = term;
    __syncthreads();
    if (tid == 0) out[b] = red[0] + red[1] + red[2] + red[3] + fc_b[0];
}

extern "C" void kernel_launch(void* const* d_in, const int* in_sizes, int n_in,
                              void* d_out, int out_size, void* d_ws, size_t ws_size,
                              hipStream_t stream) {
    const float* x    = (const float*)d_in[0];
    const float* W_ih = (const float*)d_in[1];
    const float* W_hh = (const float*)d_in[2];
    const float* b_ih = (const float*)d_in[3];
    const float* b_hh = (const float*)d_in[4];
    const float* fc_W = (const float*)d_in[5];
    const float* fc_b = (const float*)d_in[6];
    float* out = (float*)d_out;

    rnn_fused_kernel<<<RNN_B, 256, 0, stream>>>(x, W_ih, W_hh, b_ih, b_hh, fc_W, fc_b, out);
}

// Round 13
// 342.837 us; speedup vs baseline: 2.9109x; 2.9109x over previous
//
#include <hip/hip_runtime.h>
#include <stdint.h>

// SimpleRNN fused kernel for MI355X (gfx950).
// B=256, T=512, I=64, H=256, O=1, fp32.
//
// History (key points):
// R1: padded-LDS conflict fix 608->461us. R7: multi-j LDS-issue fix ->319us,
//     VALUBusy 96% (VALU-issue-bound: 160 FMA + ~160 v_accvgpr_read tax).
// R3-R5,R10: no source attribute forces weights into arch VGPRs; allocator
//     always AGPR-homes the cold 160-float array (or scratch-spills, R10).
// R11: PROVEN: gfx950 VALU cannot read AGPR operands (compile error).
// R12: full-asm recurrence (weights in fixed clobbered v64-v223, pk_fma
//     MACs, hand-scheduled reduce/tanh). CRASHED: the x-prefetch guard
//     (s_cmp cntt,1) let iteration 16 issue a dead global_load from
//     tile16 -- 8KB past the end of x for b=255 -> page fault.
// R13: two-line fix: (a) guard is now s_cmp cntt,2 so the address stops
//     advancing at iter 15; iter 16's dead load re-reads tile15
//     (in-bounds, unused). (b) s_waitcnt vmcnt(0) before the asm exits,
//     so the dead load's writeback to v[60:63] can't race the epilogue.

#define RNN_B 256
#define RNN_T 512
#define RNN_I 64
#define RNN_H 256

// ---- one recurrence step: reads h from RD (+x from v55), writes h_new to WR.
// Fixed regs: v[0:31] h quads, v[32:35]+v[48:51] x quads, v[36:43] acc pairs
// (jj0..3), v44-47 p0..3, v52-54 temps, v55 x read addr.
// Weights: wh jj0/1/2/3 at v[64+4c]/v[96+4c]/v[128+4c]/v[160+4c] (+2 for hi
// pair), wi jj0/1/2/3 pairs at v[192..199]/[200..207]/[208..215]/[216..223].
#define STEP(RD, WR) \
  "ds_read_b128 v[0:3], "   RD " offset:0\n\t" \
  "ds_read_b128 v[4:7], "   RD " offset:16\n\t" \
  "ds_read_b128 v[8:11], "  RD " offset:32\n\t" \
  "ds_read_b128 v[12:15], " RD " offset:48\n\t" \
  "ds_read_b128 v[16:19], " RD " offset:64\n\t" \
  "ds_read_b128 v[20:23], " RD " offset:80\n\t" \
  "ds_read_b128 v[24:27], " RD " offset:96\n\t" \
  "ds_read_b128 v[28:31], " RD " offset:112\n\t" \
  "ds_read_b128 v[32:35], v55 offset:0\n\t" \
  "ds_read_b128 v[48:51], v55 offset:16\n\t" \
  "v_add_u32 v55, 0x100, v55\n\t" \
  "s_waitcnt lgkmcnt(6)\n\t" \
  "v_pk_mul_f32 v[36:37], v[0:1], v[64:65]\n\t" \
  "v_pk_mul_f32 v[38:39], v[0:1], v[96:97]\n\t" \
  "v_pk_mul_f32 v[40:41], v[0:1], v[128:129]\n\t" \
  "v_pk_mul_f32 v[42:43], v[0:1], v[160:161]\n\t" \
  "v_pk_fma_f32 v[36:37], v[2:3], v[66:67], v[36:37]\n\t" \
  "v_pk_fma_f32 v[38:39], v[2:3], v[98:99], v[38:39]\n\t" \
  "v_pk_fma_f32 v[40:41], v[2:3], v[130:131], v[40:41]\n\t" \
  "v_pk_fma_f32 v[42:43], v[2:3], v[162:163], v[42:43]\n\t" \
  "v_pk_fma_f32 v[36:37], v[4:5], v[68:69], v[36:37]\n\t" \
  "v_pk_fma_f32 v[38:39], v[4:5], v[100:101], v[38:39]\n\t" \
  "v_pk_fma_f32 v[40:41], v[4:5], v[132:133], v[40:41]\n\t" \
  "v_pk_fma_f32 v[42:43], v[4:5], v[164:165], v[42:43]\n\t" \
  "v_pk_fma_f32 v[36:37], v[6:7], v[70:71], v[36:37]\n\t" \
  "v_pk_fma_f32 v[38:39], v[6:7], v[102:103], v[38:39]\n\t" \
  "v_pk_fma_f32 v[40:41], v[6:7], v[134:135], v[40:41]\n\t" \
  "v_pk_fma_f32 v[42:43], v[6:7], v[166:167], v[42:43]\n\t" \
  "v_pk_fma_f32 v[36:37], v[8:9], v[72:73], v[36:37]\n\t" \
  "v_pk_fma_f32 v[38:39], v[8:9], v[104:105], v[38:39]\n\t" \
  "v_pk_fma_f32 v[40:41], v[8:9], v[136:137], v[40:41]\n\t" \
  "v_pk_fma_f32 v[42:43], v[8:9], v[168:169], v[42:43]\n\t" \
  "v_pk_fma_f32 v[36:37], v[10:11], v[74:75], v[36:37]\n\t" \
  "v_pk_fma_f32 v[38:39], v[10:11], v[106:107], v[38:39]\n\t" \
  "v_pk_fma_f32 v[40:41], v[10:11], v[138:139], v[40:41]\n\t" \
  "v_pk_fma_f32 v[42:43], v[10:11], v[170:171], v[42:43]\n\t" \
  "v_pk_fma_f32 v[36:37], v[12:13], v[76:77], v[36:37]\n\t" \
  "v_pk_fma_f32 v[38:39], v[12:13], v[108:109], v[38:39]\n\t" \
  "v_pk_fma_f32 v[40:41], v[12:13], v[140:141], v[40:41]\n\t" \
  "v_pk_fma_f32 v[42:43], v[12:13], v[172:173], v[42:43]\n\t" \
  "v_pk_fma_f32 v[36:37], v[14:15], v[78:79], v[36:37]\n\t" \
  "v_pk_fma_f32 v[38:39], v[14:15], v[110:111], v[38:39]\n\t" \
  "v_pk_fma_f32 v[40:41], v[14:15], v[142:143], v[40:41]\n\t" \
  "v_pk_fma_f32 v[42:43], v[14:15], v[174:175], v[42:43]\n\t" \
  "s_waitcnt lgkmcnt(2)\n\t" \
  "v_pk_fma_f32 v[36:37], v[16:17], v[80:81], v[36:37]\n\t" \
  "v_pk_fma_f32 v[38:39], v[16:17], v[112:113], v[38:39]\n\t" \
  "v_pk_fma_f32 v[40:41], v[16:17], v[144:145], v[40:41]\n\t" \
  "v_pk_fma_f32 v[42:43], v[16:17], v[176:177], v[42:43]\n\t" \
  "v_pk_fma_f32 v[36:37], v[18:19], v[82:83], v[36:37]\n\t" \
  "v_pk_fma_f32 v[38:39], v[18:19], v[114:115], v[38:39]\n\t" \
  "v_pk_fma_f32 v[40:41], v[18:19], v[146:147], v[40:41]\n\t" \
  "v_pk_fma_f32 v[42:43], v[18:19], v[178:179], v[42:43]\n\t" \
  "v_pk_fma_f32 v[36:37], v[20:21], v[84:85], v[36:37]\n\t" \
  "v_pk_fma_f32 v[38:39], v[20:21], v[116:117], v[38:39]\n\t" \
  "v_pk_fma_f32 v[40:41], v[20:21], v[148:149], v[40:41]\n\t" \
  "v_pk_fma_f32 v[42:43], v[20:21], v[180:181], v[42:43]\n\t" \
  "v_pk_fma_f32 v[36:37], v[22:23], v[86:87], v[36:37]\n\t" \
  "v_pk_fma_f32 v[38:39], v[22:23], v[118:119], v[38:39]\n\t" \
  "v_pk_fma_f32 v[40:41], v[22:23], v[150:151], v[40:41]\n\t" \
  "v_pk_fma_f32 v[42:43], v[22:23], v[182:183], v[42:43]\n\t" \
  "v_pk_fma_f32 v[36:37], v[24:25], v[88:89], v[36:37]\n\t" \
  "v_pk_fma_f32 v[38:39], v[24:25], v[120:121], v[38:39]\n\t" \
  "v_pk_fma_f32 v[40:41], v[24:25], v[152:153], v[40:41]\n\t" \
  "v_pk_fma_f32 v[42:43], v[24:25], v[184:185], v[42:43]\n\t" \
  "v_pk_fma_f32 v[36:37], v[26:27], v[90:91], v[36:37]\n\t" \
  "v_pk_fma_f32 v[38:39], v[26:27], v[122:123], v[38:39]\n\t" \
  "v_pk_fma_f32 v[40:41], v[26:27], v[154:155], v[40:41]\n\t" \
  "v_pk_fma_f32 v[42:43], v[26:27], v[186:187], v[42:43]\n\t" \
  "v_pk_fma_f32 v[36:37], v[28:29], v[92:93], v[36:37]\n\t" \
  "v_pk_fma_f32 v[38:39], v[28:29], v[124:125], v[38:39]\n\t" \
  "v_pk_fma_f32 v[40:41], v[28:29], v[156:157], v[40:41]\n\t" \
  "v_pk_fma_f32 v[42:43], v[28:29], v[188:189], v[42:43]\n\t" \
  "v_pk_fma_f32 v[36:37], v[30:31], v[94:95], v[36:37]\n\t" \
  "v_pk_fma_f32 v[38:39], v[30:31], v[126:127], v[38:39]\n\t" \
  "v_pk_fma_f32 v[40:41], v[30:31], v[158:159], v[40:41]\n\t" \
  "v_pk_fma_f32 v[42:43], v[30:31], v[190:191], v[42:43]\n\t" \
  "s_waitcnt lgkmcnt(0)\n\t" \
  "v_pk_fma_f32 v[36:37], v[32:33], v[192:193], v[36:37]\n\t" \
  "v_pk_fma_f32 v[38:39], v[32:33], v[200:201], v[38:39]\n\t" \
  "v_pk_fma_f32 v[40:41], v[32:33], v[208:209], v[40:41]\n\t" \
  "v_pk_fma_f32 v[42:43], v[32:33], v[216:217], v[42:43]\n\t" \
  "v_pk_fma_f32 v[36:37], v[34:35], v[194:195], v[36:37]\n\t" \
  "v_pk_fma_f32 v[38:39], v[34:35], v[202:203], v[38:39]\n\t" \
  "v_pk_fma_f32 v[40:41], v[34:35], v[210:211], v[40:41]\n\t" \
  "v_pk_fma_f32 v[42:43], v[34:35], v[218:219], v[42:43]\n\t" \
  "v_pk_fma_f32 v[36:37], v[48:49], v[196:197], v[36:37]\n\t" \
  "v_pk_fma_f32 v[38:39], v[48:49], v[204:205], v[38:39]\n\t" \
  "v_pk_fma_f32 v[40:41], v[48:49], v[212:213], v[40:41]\n\t" \
  "v_pk_fma_f32 v[42:43], v[48:49], v[220:221], v[42:43]\n\t" \
  "v_pk_fma_f32 v[36:37], v[50:51], v[198:199], v[36:37]\n\t" \
  "v_pk_fma_f32 v[38:39], v[50:51], v[206:207], v[38:39]\n\t" \
  "v_pk_fma_f32 v[40:41], v[50:51], v[214:215], v[40:41]\n\t" \
  "v_pk_fma_f32 v[42:43], v[50:51], v[222:223], v[42:43]\n\t" \
  "v_add_f32 v44, v36, v37\n\t" \
  "v_add_f32 v45, v38, v39\n\t" \
  "v_add_f32 v46, v40, v41\n\t" \
  "v_add_f32 v47, v42, v43\n\t" \
  "v_cndmask_b32 v52, v46, v44, %[m1]\n\t" \
  "v_cndmask_b32 v44, v44, v46, %[m1]\n\t" \
  "v_cndmask_b32 v53, v47, v45, %[m1]\n\t" \
  "v_cndmask_b32 v45, v45, v47, %[m1]\n\t" \
  "ds_bpermute_b32 v52, %[bp1], v52\n\t" \
  "ds_bpermute_b32 v53, %[bp1], v53\n\t" \
  "s_waitcnt lgkmcnt(0)\n\t" \
  "v_add_f32 v44, v44, v52\n\t" \
  "v_add_f32 v45, v45, v53\n\t" \
  "v_cndmask_b32 v52, v45, v44, %[m2]\n\t" \
  "v_cndmask_b32 v44, v44, v45, %[m2]\n\t" \
  "ds_bpermute_b32 v52, %[bp2], v52\n\t" \
  "s_waitcnt lgkmcnt(0)\n\t" \
  "v_add_f32 v44, v44, v52\n\t" \
  "ds_bpermute_b32 v52, %[bp4], v44\n\t" \
  "s_waitcnt lgkmcnt(0)\n\t" \
  "v_add_f32 v44, v44, v52\n\t" \
  "v_add_f32 v44, %[bias], v44\n\t" \
  "v_max_f32 v44, %[klo], v44\n\t" \
  "v_min_f32 v44, %[khi], v44\n\t" \
  "v_mul_f32 v44, %[km], v44\n\t" \
  "v_exp_f32 v53, v44\n\t" \
  "s_nop 1\n\t" \
  "v_subrev_f32 v54, 1.0, v53\n\t" \
  "v_add_f32 v53, 1.0, v53\n\t" \
  "v_rcp_f32 v53, v53\n\t" \
  "s_nop 1\n\t" \
  "v_mul_f32 v54, v54, v53\n\t" \
  "v_mov_b32 %[hj], v54\n\t" \
  "ds_write_b32 " WR ", v54\n\t" \
  "s_waitcnt lgkmcnt(0)\n\t" \
  "s_barrier\n\t"

__global__
__attribute__((amdgpu_flat_work_group_size(512, 512), amdgpu_waves_per_eu(2, 2)))
void rnn_fused_kernel(const float* __restrict__ x,     // [B,T,I]
                      const float* __restrict__ W_ih,  // [H,I]
                      const float* __restrict__ W_hh,  // [H,H]
                      const float* __restrict__ b_ih,  // [H]
                      const float* __restrict__ b_hh,  // [H]
                      const float* __restrict__ fc_W,  // [O,H], O=1
                      const float* __restrict__ fc_b,  // [O]
                      float* __restrict__ out)         // [B,O]
{
    const int b   = blockIdx.x;
    const int tid = threadIdx.x;    // 0..511
    const int w   = tid >> 6;       // wave 0..7
    const int l   = tid & 63;       // lane
    const int g   = l >> 3;         // j-quad within wave, 0..7
    const int s   = l & 7;          // k-segment, 0..7
    const int j0  = w * 32 + g * 4; // first j of this lane's quad

    __shared__ float hbuf[2][320];     // padded h + dummy slots 288..319
    __shared__ float xt[32][RNN_I];    // x tile: 32 timesteps, 8 KB
    __shared__ float red[8];

    // lane finalizes j_fin = j0 + jjsel after the reduce-scatter (R7 layout)
    const int   jjsel = ((s & 1) << 1) | ((s >> 1) & 1);
    const int   j_fin = j0 + jjsel;
    const int   jslot = j_fin + 4 * w;                    // slot(j)=j+4*(j>>5)
    const int   wslot = (s < 4) ? jslot : (288 + (l & 31)); // dummy for s>=4
    const float bias2 = b_ih[j_fin] + b_hh[j_fin];
    const float fcw   = fc_W[j_fin];

    // LDS byte addresses (generic->LDS: aperture is 4GB-aligned, low32 = offset)
    const uint32_t hb   = (uint32_t)(uintptr_t)&hbuf[0][0];
    const uint32_t xtb  = (uint32_t)(uintptr_t)&xt[0][0];
    const uint32_t hrd0 = hb + 144u * (uint32_t)s;
    const uint32_t hrd1 = hb + 1280u + 144u * (uint32_t)s;
    const uint32_t hwr0 = hb + 4u * (uint32_t)wslot;
    const uint32_t hwr1 = hb + 1280u + 4u * (uint32_t)wslot;
    const uint32_t xst  = xtb + 16u * (uint32_t)tid;
    const uint32_t xrd0 = xtb + 32u * (uint32_t)s;

    // cross-lane helpers
    const uint32_t bp1 = (uint32_t)((l ^ 1) << 2);
    const uint32_t bp2 = (uint32_t)((l ^ 2) << 2);
    const uint32_t bp4 = (uint32_t)((l ^ 4) << 2);
    const unsigned long long m1 = __ballot(s & 1);
    const unsigned long long m2 = __ballot(s & 2);

    // global pointers (passed as lo/hi so the asm can do 64-bit adds)
    const float* whp = W_hh + (size_t)j0 * RNN_H + 32 * s;
    const float* wip = W_ih + (size_t)j0 * RNN_I + 8 * s;
    const float* xgp = x + (size_t)b * RNN_T * RNN_I + 4 * tid;
    const uint32_t whlo = (uint32_t)(uintptr_t)whp, whhi = (uint32_t)((uintptr_t)whp >> 32);
    const uint32_t wilo = (uint32_t)(uintptr_t)wip, wihi = (uint32_t)((uintptr_t)wip >> 32);
    const uint32_t xglo = (uint32_t)(uintptr_t)xgp, xghi = (uint32_t)((uintptr_t)xgp >> 32);

    // prologue: h0 = 0 (covers dummy region too)
    if (tid < 320) hbuf[0][tid] = 0.0f;
    __syncthreads();

    float hj = 0.0f;
    int cntt, cnts, sadv;
    const float khi = 10.0f, klo = -10.0f, km = 2.8853900817779268f;

    asm volatile(
        // ---- load weights into fixed regs v64..v223 (once) ----
        "v_mov_b32 v56, %[whlo]\n\t"
        "v_mov_b32 v57, %[whhi]\n\t"
        "global_load_dwordx4 v[64:67],   v[56:57], off\n\t"
        "global_load_dwordx4 v[68:71],   v[56:57], off offset:16\n\t"
        "global_load_dwordx4 v[72:75],   v[56:57], off offset:32\n\t"
        "global_load_dwordx4 v[76:79],   v[56:57], off offset:48\n\t"
        "global_load_dwordx4 v[80:83],   v[56:57], off offset:64\n\t"
        "global_load_dwordx4 v[84:87],   v[56:57], off offset:80\n\t"
        "global_load_dwordx4 v[88:91],   v[56:57], off offset:96\n\t"
        "global_load_dwordx4 v[92:95],   v[56:57], off offset:112\n\t"
        "global_load_dwordx4 v[96:99],   v[56:57], off offset:1024\n\t"
        "global_load_dwordx4 v[100:103], v[56:57], off offset:1040\n\t"
        "global_load_dwordx4 v[104:107], v[56:57], off offset:1056\n\t"
        "global_load_dwordx4 v[108:111], v[56:57], off offset:1072\n\t"
        "global_load_dwordx4 v[112:115], v[56:57], off offset:1088\n\t"
        "global_load_dwordx4 v[116:119], v[56:57], off offset:1104\n\t"
        "global_load_dwordx4 v[120:123], v[56:57], off offset:1120\n\t"
        "global_load_dwordx4 v[124:127], v[56:57], off offset:1136\n\t"
        "global_load_dwordx4 v[128:131], v[56:57], off offset:2048\n\t"
        "global_load_dwordx4 v[132:135], v[56:57], off offset:2064\n\t"
        "global_load_dwordx4 v[136:139], v[56:57], off offset:2080\n\t"
        "global_load_dwordx4 v[140:143], v[56:57], off offset:2096\n\t"
        "global_load_dwordx4 v[144:147], v[56:57], off offset:2112\n\t"
        "global_load_dwordx4 v[148:151], v[56:57], off offset:2128\n\t"
        "global_load_dwordx4 v[152:155], v[56:57], off offset:2144\n\t"
        "global_load_dwordx4 v[156:159], v[56:57], off offset:2160\n\t"
        "global_load_dwordx4 v[160:163], v[56:57], off offset:3072\n\t"
        "global_load_dwordx4 v[164:167], v[56:57], off offset:3088\n\t"
        "global_load_dwordx4 v[168:171], v[56:57], off offset:3104\n\t"
        "global_load_dwordx4 v[172:175], v[56:57], off offset:3120\n\t"
        "global_load_dwordx4 v[176:179], v[56:57], off offset:3136\n\t"
        "global_load_dwordx4 v[180:183], v[56:57], off offset:3152\n\t"
        "global_load_dwordx4 v[184:187], v[56:57], off offset:3168\n\t"
        "global_load_dwordx4 v[188:191], v[56:57], off offset:3184\n\t"
        "v_mov_b32 v56, %[wilo]\n\t"
        "v_mov_b32 v57, %[wihi]\n\t"
        "global_load_dwordx4 v[192:195], v[56:57], off\n\t"
        "global_load_dwordx4 v[196:199], v[56:57], off offset:16\n\t"
        "global_load_dwordx4 v[200:203], v[56:57], off offset:256\n\t"
        "global_load_dwordx4 v[204:207], v[56:57], off offset:272\n\t"
        "global_load_dwordx4 v[208:211], v[56:57], off offset:512\n\t"
        "global_load_dwordx4 v[212:215], v[56:57], off offset:528\n\t"
        "global_load_dwordx4 v[216:219], v[56:57], off offset:768\n\t"
        "global_load_dwordx4 v[220:223], v[56:57], off offset:784\n\t"
        // ---- x prefetch pipeline (v58:59 addr, v60:63 data) ----
        "v_mov_b32 v58, %[xglo]\n\t"
        "v_mov_b32 v59, %[xghi]\n\t"
        "global_load_dwordx4 v[60:63], v[58:59], off\n\t"
        "v_add_co_u32 v58, vcc, 0x2000, v58\n\t"
        "v_addc_co_u32 v59, vcc, 0, v59, vcc\n\t"
        "s_mov_b32 %[cntt], 16\n\t"
        "LTILE%=:\n\t"
        "s_waitcnt vmcnt(0)\n\t"
        "ds_write_b128 %[xst], v[60:63]\n\t"
        "global_load_dwordx4 v[60:63], v[58:59], off\n\t"
        // R13 fix: stop ADVANCING at cntt==2 so the (dead) load of the
        // final iteration re-reads tile15 instead of stepping past the
        // end of x (page fault at b=255).
        "s_cmp_lg_u32 %[cntt], 2\n\t"
        "s_cselect_b32 %[sadv], 0x2000, 0\n\t"
        "v_add_co_u32 v58, vcc, %[sadv], v58\n\t"
        "v_addc_co_u32 v59, vcc, 0, v59, vcc\n\t"
        "v_mov_b32 v55, %[xrd0]\n\t"
        "s_waitcnt lgkmcnt(0)\n\t"
        "s_barrier\n\t"
        "s_mov_b32 %[cnts], 16\n\t"
        "LSTEP%=:\n\t"
        STEP("%[hrd0]", "%[hwr1]")
        STEP("%[hrd1]", "%[hwr0]")
        "s_sub_u32 %[cnts], %[cnts], 1\n\t"
        "s_cmp_lg_u32 %[cnts], 0\n\t"
        "s_cbranch_scc1 LSTEP%=\n\t"
        "s_sub_u32 %[cntt], %[cntt], 1\n\t"
        "s_cmp_lg_u32 %[cntt], 0\n\t"
        "s_cbranch_scc1 LTILE%=\n\t"
        // R13 fix: drain the final (dead) x load so its writeback to
        // v[60:63] cannot race whatever the compiler puts there next.
        "s_waitcnt vmcnt(0)\n\t"
        : [hj] "+v"(hj), [cntt] "=&s"(cntt), [cnts] "=&s"(cnts), [sadv] "=&s"(sadv)
        : [whlo] "v"(whlo), [whhi] "v"(whhi), [wilo] "v"(wilo), [wihi] "v"(wihi),
          [xglo] "v"(xglo), [xghi] "v"(xghi), [xst] "v"(xst), [xrd0] "v"(xrd0),
          [hrd0] "v"(hrd0), [hrd1] "v"(hrd1), [hwr0] "v"(hwr0), [hwr1] "v"(hwr1),
          [bp1] "v"(bp1), [bp2] "v"(bp2), [bp4] "v"(bp4), [bias] "v"(bias2),
          [m1] "s"(m1), [m2] "s"(m2),
          [khi] "s"(khi), [klo] "s"(klo), [km] "s"(km)
        : "memory", "vcc", "scc",
          "v0","v1","v2","v3","v4","v5","v6","v7","v8","v9",
          "v10","v11","v12","v13","v14","v15","v16","v17","v18","v19",
          "v20","v21","v22","v23","v24","v25","v26","v27","v28","v29",
          "v30","v31","v32","v33","v34","v35","v36","v37","v38","v39",
          "v40","v41","v42","v43","v44","v45","v46","v47","v48","v49",
          "v50","v51","v52","v53","v54","v55","v56","v57","v58","v59",
          "v60","v61","v62","v63","v64","v65","v66","v67","v68","v69",
          "v70","v71","v72","v73","v74","v75","v76","v77","v78","v79",
          "v80","v81","v82","v83","v84","v85","v86","v87","v88","v89",
          "v90","v91","v92","v93","v94","v95","v96","v97","v98","v99",
          "v100","v101","v102","v103","v104","v105","v106","v107","v108","v109",
          "v110","v111","v112","v113","v114","v115","v116","v117","v118","v119",
          "v120","v121","v122","v123","v124","v125","v126","v127","v128","v129",
          "v130","v131","v132","v133","v134","v135","v136","v137","v138","v139",
          "v140","v141","v142","v143","v144","v145","v146","v147","v148","v149",
          "v150","v151","v152","v153","v154","v155","v156","v157","v158","v159",
          "v160","v161","v162","v163","v164","v165","v166","v167","v168","v169",
          "v170","v171","v172","v173","v174","v175","v176","v177","v178","v179",
          "v180","v181","v182","v183","v184","v185","v186","v187","v188","v189",
          "v190","v191","v192","v193","v194","v195","v196","v197","v198","v199",
          "v200","v201","v202","v203","v204","v205","v206","v207","v208","v209",
          "v210","v211","v212","v213","v214","v215","v216","v217","v218","v219",
          "v220","v221","v222","v223");

    // ---- epilogue: out[b] = sum_j h_T[j]*fc_W[j] + fc_b ----
    float term = (s < 4) ? hj * fcw : 0.0f;   // each j counted once
    #pragma unroll
    for (int d = 1; d < 64; d <<= 1) term += __shfl_xor(term, d, 64);
    if (l == 0) red[w] = term;
    __syncthreads();
    if (tid == 0) {
        float sum = 0.f;
        #pragma unroll
        for (int ww = 0; ww < 8; ++ww) sum += red[ww];
        out[b] = sum + fc_b[0];
    }
}

extern "C" void kernel_launch(void* const* d_in, const int* in_sizes, int n_in,
                              void* d_out, int out_size, void* d_ws, size_t ws_size,
                              hipStream_t stream) {
    const float* x    = (const float*)d_in[0];
    const float* W_ih = (const float*)d_in[1];
    const float* W_hh = (const float*)d_in[2];
    const float* b_ih = (const float*)d_in[3];
    const float* b_hh = (const float*)d_in[4];
    const float* fc_W = (const float*)d_in[5];
    const float* fc_b = (const float*)d_in[6];
    float* out = (float*)d_out;

    rnn_fused_kernel<<<RNN_B, 512, 0, stream>>>(x, W_ih, W_hh, b_ih, b_hh, fc_W, fc_b, out);
}

// Round 14
// 321.601 us; speedup vs baseline: 3.1031x; 1.0660x over previous
//
#include <hip/hip_runtime.h>
#include <stdint.h>

// SimpleRNN fused kernel for MI355X (gfx950).
// B=256, T=512, I=64, H=256, O=1, fp32.
//
// History (key points):
// R1: padded-LDS conflict fix 608->461us. R7: multi-j LDS-issue fix ->319us,
//     VALUBusy 96% (VALU-issue-bound: 160 FMA + ~160 v_accvgpr_read tax).
// R11: PROVEN: gfx950 VALU cannot read AGPR operands.
// R12/R13: full-asm recurrence, weights in fixed clobbered v64-v223 ->
//     tax gone (VALUBusy 50%, ~926 VALU cyc/step) but 343us: the serial
//     step-tail is now exposed (926 stall cyc/step): 3 ds_bpermute round
//     trips in the reduce, coarse lgkmcnt(6) front wait, and x-read bank
//     alias (2.1e6 conflicts = 16 cyc/step).
// R14: shorten the exposed tail, structure otherwise identical:
//     (a) xor1/xor2 via DPP quad_perm (VALU-only) -- only xor4 keeps an
//         LDS trip (ds_swizzle 0x101F). Removes 2 LDS round trips/step.
//     (b) fine-grained front waits lgkmcnt(9..0), one per FMA group.
//     (c) x tile stride 272B + 16B pad at s=4 -> conflict-free x reads.

#define RNN_B 256
#define RNN_T 512
#define RNN_I 64
#define RNN_H 256

// ---- one recurrence step: reads h from RD (+x from v55), writes h_new to WR.
// v[0:31] h quads, v[32:35]+v[48:51] x quads, v[36:43] acc pairs,
// v44-47 p0..3, v52-54 temps, v55 x read addr.
// wh jj0/1/2/3 at v[64+4c]/v[96+4c]/v[128+4c]/v[160+4c] (lo pair, +2 hi),
// wi jj0/1/2/3 at v[192..199]/[200..207]/[208..215]/[216..223].
#define STEP(RD, WR) \
  "ds_read_b128 v[0:3], "   RD " offset:0\n\t" \
  "ds_read_b128 v[4:7], "   RD " offset:16\n\t" \
  "ds_read_b128 v[8:11], "  RD " offset:32\n\t" \
  "ds_read_b128 v[12:15], " RD " offset:48\n\t" \
  "ds_read_b128 v[16:19], " RD " offset:64\n\t" \
  "ds_read_b128 v[20:23], " RD " offset:80\n\t" \
  "ds_read_b128 v[24:27], " RD " offset:96\n\t" \
  "ds_read_b128 v[28:31], " RD " offset:112\n\t" \
  "ds_read_b128 v[32:35], v55 offset:0\n\t" \
  "ds_read_b128 v[48:51], v55 offset:16\n\t" \
  "v_add_u32 v55, 0x110, v55\n\t" \
  "s_waitcnt lgkmcnt(9)\n\t" \
  "v_pk_mul_f32 v[36:37], v[0:1], v[64:65]\n\t" \
  "v_pk_mul_f32 v[38:39], v[0:1], v[96:97]\n\t" \
  "v_pk_mul_f32 v[40:41], v[0:1], v[128:129]\n\t" \
  "v_pk_mul_f32 v[42:43], v[0:1], v[160:161]\n\t" \
  "v_pk_fma_f32 v[36:37], v[2:3], v[66:67], v[36:37]\n\t" \
  "v_pk_fma_f32 v[38:39], v[2:3], v[98:99], v[38:39]\n\t" \
  "v_pk_fma_f32 v[40:41], v[2:3], v[130:131], v[40:41]\n\t" \
  "v_pk_fma_f32 v[42:43], v[2:3], v[162:163], v[42:43]\n\t" \
  "s_waitcnt lgkmcnt(8)\n\t" \
  "v_pk_fma_f32 v[36:37], v[4:5], v[68:69], v[36:37]\n\t" \
  "v_pk_fma_f32 v[38:39], v[4:5], v[100:101], v[38:39]\n\t" \
  "v_pk_fma_f32 v[40:41], v[4:5], v[132:133], v[40:41]\n\t" \
  "v_pk_fma_f32 v[42:43], v[4:5], v[164:165], v[42:43]\n\t" \
  "v_pk_fma_f32 v[36:37], v[6:7], v[70:71], v[36:37]\n\t" \
  "v_pk_fma_f32 v[38:39], v[6:7], v[102:103], v[38:39]\n\t" \
  "v_pk_fma_f32 v[40:41], v[6:7], v[134:135], v[40:41]\n\t" \
  "v_pk_fma_f32 v[42:43], v[6:7], v[166:167], v[42:43]\n\t" \
  "s_waitcnt lgkmcnt(7)\n\t" \
  "v_pk_fma_f32 v[36:37], v[8:9], v[72:73], v[36:37]\n\t" \
  "v_pk_fma_f32 v[38:39], v[8:9], v[104:105], v[38:39]\n\t" \
  "v_pk_fma_f32 v[40:41], v[8:9], v[136:137], v[40:41]\n\t" \
  "v_pk_fma_f32 v[42:43], v[8:9], v[168:169], v[42:43]\n\t" \
  "v_pk_fma_f32 v[36:37], v[10:11], v[74:75], v[36:37]\n\t" \
  "v_pk_fma_f32 v[38:39], v[10:11], v[106:107], v[38:39]\n\t" \
  "v_pk_fma_f32 v[40:41], v[10:11], v[138:139], v[40:41]\n\t" \
  "v_pk_fma_f32 v[42:43], v[10:11], v[170:171], v[42:43]\n\t" \
  "s_waitcnt lgkmcnt(6)\n\t" \
  "v_pk_fma_f32 v[36:37], v[12:13], v[76:77], v[36:37]\n\t" \
  "v_pk_fma_f32 v[38:39], v[12:13], v[108:109], v[38:39]\n\t" \
  "v_pk_fma_f32 v[40:41], v[12:13], v[140:141], v[40:41]\n\t" \
  "v_pk_fma_f32 v[42:43], v[12:13], v[172:173], v[42:43]\n\t" \
  "v_pk_fma_f32 v[36:37], v[14:15], v[78:79], v[36:37]\n\t" \
  "v_pk_fma_f32 v[38:39], v[14:15], v[110:111], v[38:39]\n\t" \
  "v_pk_fma_f32 v[40:41], v[14:15], v[142:143], v[40:41]\n\t" \
  "v_pk_fma_f32 v[42:43], v[14:15], v[174:175], v[42:43]\n\t" \
  "s_waitcnt lgkmcnt(5)\n\t" \
  "v_pk_fma_f32 v[36:37], v[16:17], v[80:81], v[36:37]\n\t" \
  "v_pk_fma_f32 v[38:39], v[16:17], v[112:113], v[38:39]\n\t" \
  "v_pk_fma_f32 v[40:41], v[16:17], v[144:145], v[40:41]\n\t" \
  "v_pk_fma_f32 v[42:43], v[16:17], v[176:177], v[42:43]\n\t" \
  "v_pk_fma_f32 v[36:37], v[18:19], v[82:83], v[36:37]\n\t" \
  "v_pk_fma_f32 v[38:39], v[18:19], v[114:115], v[38:39]\n\t" \
  "v_pk_fma_f32 v[40:41], v[18:19], v[146:147], v[40:41]\n\t" \
  "v_pk_fma_f32 v[42:43], v[18:19], v[178:179], v[42:43]\n\t" \
  "s_waitcnt lgkmcnt(4)\n\t" \
  "v_pk_fma_f32 v[36:37], v[20:21], v[84:85], v[36:37]\n\t" \
  "v_pk_fma_f32 v[38:39], v[20:21], v[116:117], v[38:39]\n\t" \
  "v_pk_fma_f32 v[40:41], v[20:21], v[148:149], v[40:41]\n\t" \
  "v_pk_fma_f32 v[42:43], v[20:21], v[180:181], v[42:43]\n\t" \
  "v_pk_fma_f32 v[36:37], v[22:23], v[86:87], v[36:37]\n\t" \
  "v_pk_fma_f32 v[38:39], v[22:23], v[118:119], v[38:39]\n\t" \
  "v_pk_fma_f32 v[40:41], v[22:23], v[150:151], v[40:41]\n\t" \
  "v_pk_fma_f32 v[42:43], v[22:23], v[182:183], v[42:43]\n\t" \
  "s_waitcnt lgkmcnt(3)\n\t" \
  "v_pk_fma_f32 v[36:37], v[24:25], v[88:89], v[36:37]\n\t" \
  "v_pk_fma_f32 v[38:39], v[24:25], v[120:121], v[38:39]\n\t" \
  "v_pk_fma_f32 v[40:41], v[24:25], v[152:153], v[40:41]\n\t" \
  "v_pk_fma_f32 v[42:43], v[24:25], v[184:185], v[42:43]\n\t" \
  "v_pk_fma_f32 v[36:37], v[26:27], v[90:91], v[36:37]\n\t" \
  "v_pk_fma_f32 v[38:39], v[26:27], v[122:123], v[38:39]\n\t" \
  "v_pk_fma_f32 v[40:41], v[26:27], v[154:155], v[40:41]\n\t" \
  "v_pk_fma_f32 v[42:43], v[26:27], v[186:187], v[42:43]\n\t" \
  "s_waitcnt lgkmcnt(2)\n\t" \
  "v_pk_fma_f32 v[36:37], v[28:29], v[92:93], v[36:37]\n\t" \
  "v_pk_fma_f32 v[38:39], v[28:29], v[124:125], v[38:39]\n\t" \
  "v_pk_fma_f32 v[40:41], v[28:29], v[156:157], v[40:41]\n\t" \
  "v_pk_fma_f32 v[42:43], v[28:29], v[188:189], v[42:43]\n\t" \
  "v_pk_fma_f32 v[36:37], v[30:31], v[94:95], v[36:37]\n\t" \
  "v_pk_fma_f32 v[38:39], v[30:31], v[126:127], v[38:39]\n\t" \
  "v_pk_fma_f32 v[40:41], v[30:31], v[158:159], v[40:41]\n\t" \
  "v_pk_fma_f32 v[42:43], v[30:31], v[190:191], v[42:43]\n\t" \
  "s_waitcnt lgkmcnt(1)\n\t" \
  "v_pk_fma_f32 v[36:37], v[32:33], v[192:193], v[36:37]\n\t" \
  "v_pk_fma_f32 v[38:39], v[32:33], v[200:201], v[38:39]\n\t" \
  "v_pk_fma_f32 v[40:41], v[32:33], v[208:209], v[40:41]\n\t" \
  "v_pk_fma_f32 v[42:43], v[32:33], v[216:217], v[42:43]\n\t" \
  "v_pk_fma_f32 v[36:37], v[34:35], v[194:195], v[36:37]\n\t" \
  "v_pk_fma_f32 v[38:39], v[34:35], v[202:203], v[38:39]\n\t" \
  "v_pk_fma_f32 v[40:41], v[34:35], v[210:211], v[40:41]\n\t" \
  "v_pk_fma_f32 v[42:43], v[34:35], v[218:219], v[42:43]\n\t" \
  "s_waitcnt lgkmcnt(0)\n\t" \
  "v_pk_fma_f32 v[36:37], v[48:49], v[196:197], v[36:37]\n\t" \
  "v_pk_fma_f32 v[38:39], v[48:49], v[204:205], v[38:39]\n\t" \
  "v_pk_fma_f32 v[40:41], v[48:49], v[212:213], v[40:41]\n\t" \
  "v_pk_fma_f32 v[42:43], v[48:49], v[220:221], v[42:43]\n\t" \
  "v_pk_fma_f32 v[36:37], v[50:51], v[198:199], v[36:37]\n\t" \
  "v_pk_fma_f32 v[38:39], v[50:51], v[206:207], v[38:39]\n\t" \
  "v_pk_fma_f32 v[40:41], v[50:51], v[214:215], v[40:41]\n\t" \
  "v_pk_fma_f32 v[42:43], v[50:51], v[222:223], v[42:43]\n\t" \
  "v_add_f32 v44, v36, v37\n\t" \
  "v_add_f32 v45, v38, v39\n\t" \
  "v_add_f32 v46, v40, v41\n\t" \
  "v_add_f32 v47, v42, v43\n\t" \
  /* xor1 via DPP quad_perm (was ds_bpermute) */ \
  "v_cndmask_b32 v52, v46, v44, %[m1]\n\t" \
  "v_cndmask_b32 v44, v44, v46, %[m1]\n\t" \
  "v_cndmask_b32 v53, v47, v45, %[m1]\n\t" \
  "v_cndmask_b32 v45, v45, v47, %[m1]\n\t" \
  "s_nop 1\n\t" \
  "v_mov_b32_dpp v52, v52 quad_perm:[1,0,3,2] row_mask:0xf bank_mask:0xf\n\t" \
  "v_mov_b32_dpp v53, v53 quad_perm:[1,0,3,2] row_mask:0xf bank_mask:0xf\n\t" \
  "v_add_f32 v44, v44, v52\n\t" \
  "v_add_f32 v45, v45, v53\n\t" \
  /* xor2 via DPP quad_perm */ \
  "v_cndmask_b32 v52, v45, v44, %[m2]\n\t" \
  "v_cndmask_b32 v44, v44, v45, %[m2]\n\t" \
  "s_nop 1\n\t" \
  "v_mov_b32_dpp v52, v52 quad_perm:[2,3,0,1] row_mask:0xf bank_mask:0xf\n\t" \
  "v_add_f32 v44, v44, v52\n\t" \
  /* xor4: the one remaining LDS trip */ \
  "ds_swizzle_b32 v52, v44 offset:0x101F\n\t" \
  "s_waitcnt lgkmcnt(0)\n\t" \
  "v_add_f32 v44, v44, v52\n\t" \
  "v_add_f32 v44, %[bias], v44\n\t" \
  "v_max_f32 v44, %[klo], v44\n\t" \
  "v_min_f32 v44, %[khi], v44\n\t" \
  "v_mul_f32 v44, %[km], v44\n\t" \
  "v_exp_f32 v53, v44\n\t" \
  "s_nop 1\n\t" \
  "v_subrev_f32 v54, 1.0, v53\n\t" \
  "v_add_f32 v53, 1.0, v53\n\t" \
  "v_rcp_f32 v53, v53\n\t" \
  "s_nop 1\n\t" \
  "v_mul_f32 v54, v54, v53\n\t" \
  "v_mov_b32 %[hj], v54\n\t" \
  "ds_write_b32 " WR ", v54\n\t" \
  "s_waitcnt lgkmcnt(0)\n\t" \
  "s_barrier\n\t"

__global__
__attribute__((amdgpu_flat_work_group_size(512, 512), amdgpu_waves_per_eu(2, 2)))
void rnn_fused_kernel(const float* __restrict__ x,     // [B,T,I]
                      const float* __restrict__ W_ih,  // [H,I]
                      const float* __restrict__ W_hh,  // [H,H]
                      const float* __restrict__ b_ih,  // [H]
                      const float* __restrict__ b_hh,  // [H]
                      const float* __restrict__ fc_W,  // [O,H], O=1
                      const float* __restrict__ fc_b,  // [O]
                      float* __restrict__ out)         // [B,O]
{
    const int b   = blockIdx.x;
    const int tid = threadIdx.x;    // 0..511
    const int w   = tid >> 6;       // wave 0..7
    const int l   = tid & 63;       // lane
    const int g   = l >> 3;         // j-quad within wave, 0..7
    const int s   = l & 7;          // k-segment, 0..7
    const int j0  = w * 32 + g * 4; // first j of this lane's quad

    __shared__ float hbuf[2][320];     // padded h + dummy slots 288..319
    __shared__ float xt[32 * 68];      // x tile: 32 rows x 272B (padded)
    __shared__ float red[8];

    // lane finalizes j_fin = j0 + jjsel after the reduce-scatter (R7 layout)
    const int   jjsel = ((s & 1) << 1) | ((s >> 1) & 1);
    const int   j_fin = j0 + jjsel;
    const int   jslot = j_fin + 4 * w;                    // slot(j)=j+4*(j>>5)
    const int   wslot = (s < 4) ? jslot : (288 + (l & 31)); // dummy for s>=4
    const float bias2 = b_ih[j_fin] + b_hh[j_fin];
    const float fcw   = fc_W[j_fin];

    // LDS byte addresses
    const uint32_t hb   = (uint32_t)(uintptr_t)&hbuf[0][0];
    const uint32_t xtb  = (uint32_t)(uintptr_t)&xt[0];
    const uint32_t hrd0 = hb + 144u * (uint32_t)s;
    const uint32_t hrd1 = hb + 1280u + 144u * (uint32_t)s;
    const uint32_t hwr0 = hb + 4u * (uint32_t)wslot;
    const uint32_t hwr1 = hb + 1280u + 4u * (uint32_t)wslot;
    // x tile layout: row t at 272B; float4 f4 of row at 16*f4 + 16*(f4>>3)
    // (16B pad between s=3 and s=4 segments -> conflict-free reads)
    const uint32_t xst  = xtb + 272u * (uint32_t)(tid >> 4)
                              + 16u * (uint32_t)(tid & 15)
                              + 16u * (uint32_t)((tid & 15) >> 3);
    const uint32_t xrd0 = xtb + 32u * (uint32_t)s + 16u * (uint32_t)(s >> 2);

    const unsigned long long m1 = __ballot(s & 1);
    const unsigned long long m2 = __ballot(s & 2);

    // global pointers
    const float* whp = W_hh + (size_t)j0 * RNN_H + 32 * s;
    const float* wip = W_ih + (size_t)j0 * RNN_I + 8 * s;
    const float* xgp = x + (size_t)b * RNN_T * RNN_I + 4 * tid;
    const uint32_t whlo = (uint32_t)(uintptr_t)whp, whhi = (uint32_t)((uintptr_t)whp >> 32);
    const uint32_t wilo = (uint32_t)(uintptr_t)wip, wihi = (uint32_t)((uintptr_t)wip >> 32);
    const uint32_t xglo = (uint32_t)(uintptr_t)xgp, xghi = (uint32_t)((uintptr_t)xgp >> 32);

    // prologue: h0 = 0 (covers dummy region too)
    if (tid < 320) hbuf[0][tid] = 0.0f;
    __syncthreads();

    float hj = 0.0f;
    int cntt, cnts, sadv;
    const float khi = 10.0f, klo = -10.0f, km = 2.8853900817779268f;

    asm volatile(
        // ---- load weights into fixed regs v64..v223 (once) ----
        "v_mov_b32 v56, %[whlo]\n\t"
        "v_mov_b32 v57, %[whhi]\n\t"
        "global_load_dwordx4 v[64:67],   v[56:57], off\n\t"
        "global_load_dwordx4 v[68:71],   v[56:57], off offset:16\n\t"
        "global_load_dwordx4 v[72:75],   v[56:57], off offset:32\n\t"
        "global_load_dwordx4 v[76:79],   v[56:57], off offset:48\n\t"
        "global_load_dwordx4 v[80:83],   v[56:57], off offset:64\n\t"
        "global_load_dwordx4 v[84:87],   v[56:57], off offset:80\n\t"
        "global_load_dwordx4 v[88:91],   v[56:57], off offset:96\n\t"
        "global_load_dwordx4 v[92:95],   v[56:57], off offset:112\n\t"
        "global_load_dwordx4 v[96:99],   v[56:57], off offset:1024\n\t"
        "global_load_dwordx4 v[100:103], v[56:57], off offset:1040\n\t"
        "global_load_dwordx4 v[104:107], v[56:57], off offset:1056\n\t"
        "global_load_dwordx4 v[108:111], v[56:57], off offset:1072\n\t"
        "global_load_dwordx4 v[112:115], v[56:57], off offset:1088\n\t"
        "global_load_dwordx4 v[116:119], v[56:57], off offset:1104\n\t"
        "global_load_dwordx4 v[120:123], v[56:57], off offset:1120\n\t"
        "global_load_dwordx4 v[124:127], v[56:57], off offset:1136\n\t"
        "global_load_dwordx4 v[128:131], v[56:57], off offset:2048\n\t"
        "global_load_dwordx4 v[132:135], v[56:57], off offset:2064\n\t"
        "global_load_dwordx4 v[136:139], v[56:57], off offset:2080\n\t"
        "global_load_dwordx4 v[140:143], v[56:57], off offset:2096\n\t"
        "global_load_dwordx4 v[144:147], v[56:57], off offset:2112\n\t"
        "global_load_dwordx4 v[148:151], v[56:57], off offset:2128\n\t"
        "global_load_dwordx4 v[152:155], v[56:57], off offset:2144\n\t"
        "global_load_dwordx4 v[156:159], v[56:57], off offset:2160\n\t"
        "global_load_dwordx4 v[160:163], v[56:57], off offset:3072\n\t"
        "global_load_dwordx4 v[164:167], v[56:57], off offset:3088\n\t"
        "global_load_dwordx4 v[168:171], v[56:57], off offset:3104\n\t"
        "global_load_dwordx4 v[172:175], v[56:57], off offset:3120\n\t"
        "global_load_dwordx4 v[176:179], v[56:57], off offset:3136\n\t"
        "global_load_dwordx4 v[180:183], v[56:57], off offset:3152\n\t"
        "global_load_dwordx4 v[184:187], v[56:57], off offset:3168\n\t"
        "global_load_dwordx4 v[188:191], v[56:57], off offset:3184\n\t"
        "v_mov_b32 v56, %[wilo]\n\t"
        "v_mov_b32 v57, %[wihi]\n\t"
        "global_load_dwordx4 v[192:195], v[56:57], off\n\t"
        "global_load_dwordx4 v[196:199], v[56:57], off offset:16\n\t"
        "global_load_dwordx4 v[200:203], v[56:57], off offset:256\n\t"
        "global_load_dwordx4 v[204:207], v[56:57], off offset:272\n\t"
        "global_load_dwordx4 v[208:211], v[56:57], off offset:512\n\t"
        "global_load_dwordx4 v[212:215], v[56:57], off offset:528\n\t"
        "global_load_dwordx4 v[216:219], v[56:57], off offset:768\n\t"
        "global_load_dwordx4 v[220:223], v[56:57], off offset:784\n\t"
        // ---- x prefetch pipeline (v58:59 addr, v60:63 data) ----
        "v_mov_b32 v58, %[xglo]\n\t"
        "v_mov_b32 v59, %[xghi]\n\t"
        "global_load_dwordx4 v[60:63], v[58:59], off\n\t"
        "v_add_co_u32 v58, vcc, 0x2000, v58\n\t"
        "v_addc_co_u32 v59, vcc, 0, v59, vcc\n\t"
        "s_mov_b32 %[cntt], 16\n\t"
        "LTILE%=:\n\t"
        "s_waitcnt vmcnt(0)\n\t"
        "ds_write_b128 %[xst], v[60:63]\n\t"
        "global_load_dwordx4 v[60:63], v[58:59], off\n\t"
        // stop ADVANCING at cntt==2 so the final (dead) load re-reads
        // tile15 instead of stepping past the end of x (R13 fix).
        "s_cmp_lg_u32 %[cntt], 2\n\t"
        "s_cselect_b32 %[sadv], 0x2000, 0\n\t"
        "v_add_co_u32 v58, vcc, %[sadv], v58\n\t"
        "v_addc_co_u32 v59, vcc, 0, v59, vcc\n\t"
        "v_mov_b32 v55, %[xrd0]\n\t"
        "s_waitcnt lgkmcnt(0)\n\t"
        "s_barrier\n\t"
        "s_mov_b32 %[cnts], 16\n\t"
        "LSTEP%=:\n\t"
        STEP("%[hrd0]", "%[hwr1]")
        STEP("%[hrd1]", "%[hwr0]")
        "s_sub_u32 %[cnts], %[cnts], 1\n\t"
        "s_cmp_lg_u32 %[cnts], 0\n\t"
        "s_cbranch_scc1 LSTEP%=\n\t"
        "s_sub_u32 %[cntt], %[cntt], 1\n\t"
        "s_cmp_lg_u32 %[cntt], 0\n\t"
        "s_cbranch_scc1 LTILE%=\n\t"
        // drain the final (dead) x load so its writeback to v[60:63]
        // cannot race the compiler's epilogue (R13 fix).
        "s_waitcnt vmcnt(0)\n\t"
        : [hj] "+v"(hj), [cntt] "=&s"(cntt), [cnts] "=&s"(cnts), [sadv] "=&s"(sadv)
        : [whlo] "v"(whlo), [whhi] "v"(whhi), [wilo] "v"(wilo), [wihi] "v"(wihi),
          [xglo] "v"(xglo), [xghi] "v"(xghi), [xst] "v"(xst), [xrd0] "v"(xrd0),
          [hrd0] "v"(hrd0), [hrd1] "v"(hrd1), [hwr0] "v"(hwr0), [hwr1] "v"(hwr1),
          [bias] "v"(bias2),
          [m1] "s"(m1), [m2] "s"(m2),
          [khi] "s"(khi), [klo] "s"(klo), [km] "s"(km)
        : "memory", "vcc", "scc",
          "v0","v1","v2","v3","v4","v5","v6","v7","v8","v9",
          "v10","v11","v12","v13","v14","v15","v16","v17","v18","v19",
          "v20","v21","v22","v23","v24","v25","v26","v27","v28","v29",
          "v30","v31","v32","v33","v34","v35","v36","v37","v38","v39",
          "v40","v41","v42","v43","v44","v45","v46","v47","v48","v49",
          "v50","v51","v52","v53","v54","v55","v56","v57","v58","v59",
          "v60","v61","v62","v63","v64","v65","v66","v67","v68","v69",
          "v70","v71","v72","v73","v74","v75","v76","v77","v78","v79",
          "v80","v81","v82","v83","v84","v85","v86","v87","v88","v89",
          "v90","v91","v92","v93","v94","v95","v96","v97","v98","v99",
          "v100","v101","v102","v103","v104","v105","v106","v107","v108","v109",
          "v110","v111","v112","v113","v114","v115","v116","v117","v118","v119",
          "v120","v121","v122","v123","v124","v125","v126","v127","v128","v129",
          "v130","v131","v132","v133","v134","v135","v136","v137","v138","v139",
          "v140","v141","v142","v143","v144","v145","v146","v147","v148","v149",
          "v150","v151","v152","v153","v154","v155","v156","v157","v158","v159",
          "v160","v161","v162","v163","v164","v165","v166","v167","v168","v169",
          "v170","v171","v172","v173","v174","v175","v176","v177","v178","v179",
          "v180","v181","v182","v183","v184","v185","v186","v187","v188","v189",
          "v190","v191","v192","v193","v194","v195","v196","v197","v198","v199",
          "v200","v201","v202","v203","v204","v205","v206","v207","v208","v209",
          "v210","v211","v212","v213","v214","v215","v216","v217","v218","v219",
          "v220","v221","v222","v223");

    // ---- epilogue: out[b] = sum_j h_T[j]*fc_W[j] + fc_b ----
    float term = (s < 4) ? hj * fcw : 0.0f;   // each j counted once
    #pragma unroll
    for (int d = 1; d < 64; d <<= 1) term += __shfl_xor(term, d, 64);
    if (l == 0) red[w] = term;
    __syncthreads();
    if (tid == 0) {
        float sum = 0.f;
        #pragma unroll
        for (int ww = 0; ww < 8; ++ww) sum += red[ww];
        out[b] = sum + fc_b[0];
    }
}

extern "C" void kernel_launch(void* const* d_in, const int* in_sizes, int n_in,
                              void* d_out, int out_size, void* d_ws, size_t ws_size,
                              hipStream_t stream) {
    const float* x    = (const float*)d_in[0];
    const float* W_ih = (const float*)d_in[1];
    const float* W_hh = (const float*)d_in[2];
    const float* b_ih = (const float*)d_in[3];
    const float* b_hh = (const float*)d_in[4];
    const float* fc_W = (const float*)d_in[5];
    const float* fc_b = (const float*)d_in[6];
    float* out = (float*)d_out;

    rnn_fused_kernel<<<RNN_B, 512, 0, stream>>>(x, W_ih, W_hh, b_ih, b_hh, fc_W, fc_b, out);
}